// Round 8
// baseline (214.093 us; speedup 1.0000x reference)
//
#include <hip/hip_runtime.h>
#include <stdint.h>

#define S_LEN 4096
#define KEEP_P 0.991f

typedef __attribute__((ext_vector_type(8)))  short bf16x8;
typedef __attribute__((ext_vector_type(16))) float f32x16;
typedef __attribute__((ext_vector_type(4)))  int   i32x4;
typedef __attribute__((ext_vector_type(2)))  int   i32x2;

static constexpr uint32_t TOTAL_N    = 4u * 4096u * 4096u;
static constexpr uint32_t MASK_WORDS = TOTAL_N / 32u;   // 8 MB bitmask
// keep  <=>  (o0^o1) < KEEP_TH  (integer form of u<0.991f; f32(0.991)=8313111*2^-23,
// u = m*2^-23 exactly (Sterbenz), so u<0.991 <=> m<8313111 <=> bits < 8313111<<9)
static constexpr uint32_t KEEP_TH = 4256312832u;        // 8313111 << 9

// ---- threefry2x32, key=(0,1), x=(0, x1): hand asm ----
// rotl(x,r) == v_alignbit_b32 x,x,32-r. Shifts: r 13,15,26,6 -> 19,17,6,26 ;
// r 17,29,16,24 -> 15,3,16,8. Validated bit-exact in round 7.

// single-chain version (fallback path only)
#define TFR_R(sh) \
  "v_add_u32 %0, %0, %1\n\t" \
  "v_alignbit_b32 %1, %1, %1, " #sh "\n\t" \
  "v_xor_b32 %1, %1, %0\n\t"

__device__ __forceinline__ uint32_t tf_xor(uint32_t x1) {
  uint32_t v0, v1;
  asm(
    "v_add_u32 %1, 1, %2\n\t"
    "v_mov_b32 %0, %1\n\t"
    "v_alignbit_b32 %1, %1, %1, 19\n\t"
    "v_xor_b32 %1, %1, %0\n\t"
    TFR_R(17) TFR_R(6) TFR_R(26)
    "v_add_u32 %0, 1, %0\n\t"
    "v_add_u32 %1, 0x1BD11BDC, %1\n\t"
    TFR_R(15) TFR_R(3) TFR_R(16) TFR_R(8)
    "v_add_u32 %0, 0x1BD11BDB, %0\n\t"
    "v_add_u32 %1, 2, %1\n\t"
    TFR_R(19) TFR_R(17) TFR_R(6) TFR_R(26)
    "v_add_u32 %1, 4, %1\n\t"
    TFR_R(15) TFR_R(3) TFR_R(16) TFR_R(8)
    "v_add_u32 %0, 1, %0\n\t"
    "v_add_u32 %1, 0x1BD11BDF, %1\n\t"
    TFR_R(19) TFR_R(17) TFR_R(6) TFR_R(26)
    "v_add_u32 %0, 0x1BD11BDB, %0\n\t"
    "v_add_u32 %1, 5, %1\n\t"
    "v_xor_b32 %0, %0, %1"
    : "=&v"(v0), "=&v"(v1) : "v"(x1));
  return v0;
}

// dual-chain version: 2 independent evals interleaved (dep distance 2)
#define TFR2(sh) \
  "v_add_u32 %0, %0, %1\n\t" \
  "v_add_u32 %2, %2, %3\n\t" \
  "v_alignbit_b32 %1, %1, %1, " #sh "\n\t" \
  "v_alignbit_b32 %3, %3, %3, " #sh "\n\t" \
  "v_xor_b32 %1, %1, %0\n\t" \
  "v_xor_b32 %3, %3, %2\n\t"

__device__ __forceinline__ void tf_xor2(uint32_t xa, uint32_t xb,
                                        uint32_t& oa, uint32_t& ob) {
  uint32_t a0, a1, b0, b1;
  asm(
    "v_add_u32 %1, 1, %4\n\t"
    "v_add_u32 %3, 1, %5\n\t"
    "v_mov_b32 %0, %1\n\t"
    "v_mov_b32 %2, %3\n\t"
    "v_alignbit_b32 %1, %1, %1, 19\n\t"
    "v_alignbit_b32 %3, %3, %3, 19\n\t"
    "v_xor_b32 %1, %1, %0\n\t"
    "v_xor_b32 %3, %3, %2\n\t"
    TFR2(17) TFR2(6) TFR2(26)
    "v_add_u32 %0, 1, %0\n\t"
    "v_add_u32 %2, 1, %2\n\t"
    "v_add_u32 %1, 0x1BD11BDC, %1\n\t"
    "v_add_u32 %3, 0x1BD11BDC, %3\n\t"
    TFR2(15) TFR2(3) TFR2(16) TFR2(8)
    "v_add_u32 %0, 0x1BD11BDB, %0\n\t"
    "v_add_u32 %2, 0x1BD11BDB, %2\n\t"
    "v_add_u32 %1, 2, %1\n\t"
    "v_add_u32 %3, 2, %3\n\t"
    TFR2(19) TFR2(17) TFR2(6) TFR2(26)
    "v_add_u32 %1, 4, %1\n\t"
    "v_add_u32 %3, 4, %3\n\t"
    TFR2(15) TFR2(3) TFR2(16) TFR2(8)
    "v_add_u32 %0, 1, %0\n\t"
    "v_add_u32 %2, 1, %2\n\t"
    "v_add_u32 %1, 0x1BD11BDF, %1\n\t"
    "v_add_u32 %3, 0x1BD11BDF, %3\n\t"
    TFR2(19) TFR2(17) TFR2(6) TFR2(26)
    "v_add_u32 %0, 0x1BD11BDB, %0\n\t"
    "v_add_u32 %2, 0x1BD11BDB, %2\n\t"
    "v_add_u32 %1, 5, %1\n\t"
    "v_add_u32 %3, 5, %3\n\t"
    "v_xor_b32 %0, %0, %1\n\t"
    "v_xor_b32 %2, %2, %3"
    : "=&v"(a0), "=&v"(a1), "=&v"(b0), "=&v"(b1)
    : "v"(xa), "v"(xb));
  oa = a0; ob = b0;
}

__device__ __forceinline__ bool keep_partitionable(uint32_t i) {
  return tf_xor(i) < KEEP_TH;
}

// word-per-thread; 16 iterations x 2 interleaved chains (bits j and j+16)
__global__ __launch_bounds__(256) void maskgen_kernel(uint32_t* __restrict__ mask) {
  uint32_t gid  = blockIdx.x * 256u + threadIdx.x;   // < MASK_WORDS
  uint32_t base = gid * 32u;
  uint32_t wlo = 0u, whi = 0u;
#pragma unroll
  for (uint32_t j = 0; j < 16u; ++j) {
    uint32_t oa, ob;
    tf_xor2(base + j, base + j + 16u, oa, ob);
    wlo |= (uint32_t)(oa < KEEP_TH) << j;
    whi |= (uint32_t)(ob < KEEP_TH) << j;
  }
  mask[gid] = wlo | (whi << 16);
}

__device__ __forceinline__ uint32_t f2u(float f){ union{float f;uint32_t u;}x; x.f=f; return x.u; }
__device__ __forceinline__ float u2f(uint32_t u){ union{uint32_t u;float f;}x; x.u=u; return x.f; }

template<bool USE_WS>
__global__ __launch_bounds__(512, 2)
void attn_mfma(const float* __restrict__ Qg, const float* __restrict__ Kg,
               const float* __restrict__ Vg, const float* __restrict__ Sdiv,
               const uint32_t* __restrict__ Mask, float* __restrict__ Out)
{
  __shared__ __align__(16) unsigned char smem[49152]; // khi 16K | klo 16K | v 16K
  __shared__ float sm_ml[2][3][2][32];
  char* khiB = (char*)smem;
  char* kloB = (char*)smem + 16384;
  char* vtsB = (char*)smem + 32768;
  float* smf = (float*)smem;   // epilogue scratch (reuse)

  const int t    = threadIdx.x;
  const int lane = t & 63;
  const int w    = t >> 6;     // wave 0..7
  const int wq   = w >> 2;     // q-group 0..1 (32 q each)
  const int h    = w & 3;      // kv quarter 0..3 (32 kv each)
  const int l31  = lane & 31;
  const int hi5  = lane >> 5;

  const int blk = blockIdx.x;
  const int xcd = blk & 7;
  const int b   = xcd >> 1;
  const int qblock = ((xcd & 1) << 5) | (blk >> 3);  // 0..63
  const int qt  = qblock * 64;

  const float inv_s = 1.0f / Sdiv[0];
  const float* Qp = Qg + (size_t)b * S_LEN * 64;
  const float* Kp = Kg + (size_t)b * S_LEN * 64;
  const float* Vp = Vg + (size_t)b * S_LEN * 64;

  // ---- stage Q (64 rows) hi/lo into khi/klo rows 0..63 (plain layout + XOR swizzle) ----
#pragma unroll
  for (int rr = 0; rr < 2; ++rr) {
    int row = rr * 32 + (t >> 4);
    int c   = (t & 15) * 4;
    float4 q4 = *(const float4*)(Qp + (size_t)(qt + row) * 64 + c);
    uint32_t u0=f2u(q4.x),u1=f2u(q4.y),u2=f2u(q4.z),u3=f2u(q4.w);
    uint32_t h01=(u1&0xFFFF0000u)|(u0>>16), h23=(u3&0xFFFF0000u)|(u2>>16);
    uint32_t l0=f2u(q4.x-u2f(u0&0xFFFF0000u)), l1=f2u(q4.y-u2f(u1&0xFFFF0000u));
    uint32_t l2=f2u(q4.z-u2f(u2&0xFFFF0000u)), l3=f2u(q4.w-u2f(u3&0xFFFF0000u));
    uint32_t lo01=(l1&0xFFFF0000u)|(l0>>16), lo23=(l3&0xFFFF0000u)|(l2>>16);
    uint32_t off = ((uint32_t)(row*128 + c*2)) ^ ((uint32_t)((row&7)<<4));
    *(i32x2*)(khiB + off) = i32x2{(int)h01,(int)h23};
    *(i32x2*)(kloB + off) = i32x2{(int)lo01,(int)lo23};
  }
  __syncthreads();
  bf16x8 qhi[4], qlo[4];
  {
    int qrow = wq * 32 + l31;
#pragma unroll
    for (int kc = 0; kc < 4; ++kc) {
      uint32_t off = ((uint32_t)(qrow*128 + kc*32 + hi5*16)) ^ ((uint32_t)((qrow&7)<<4));
      qhi[kc] = *(const bf16x8*)(khiB + off);
      qlo[kc] = *(const bf16x8*)(kloB + off);
    }
  }
  __syncthreads();

  f32x16 o0, o1;
#pragma unroll
  for (int i = 0; i < 16; ++i) { o0[i] = 0.f; o1[i] = 0.f; }
  float m = -INFINITY, lsum = 0.f;

  const int rowk = h * 32 + l31;
  const uint32_t qglob = (uint32_t)(qt + wq * 32 + l31);
  const uint32_t mrowbase = ((uint32_t)b * 4096u + qglob) * 128u;

  union PU { i32x4 i; bf16x8 bv; };

  for (int kt0 = 0; kt0 < S_LEN; kt0 += 128) {
    // ---- stage K (hi/lo, plain+swizzle) and V (plain row-major bf16 [128][64]) ----
#pragma unroll
    for (int rr = 0; rr < 4; ++rr) {
      int row = rr * 32 + (t >> 4);
      int c   = (t & 15) * 4;
      float4 k4 = *(const float4*)(Kp + (size_t)(kt0 + row) * 64 + c);
      uint32_t u0=f2u(k4.x),u1=f2u(k4.y),u2=f2u(k4.z),u3=f2u(k4.w);
      uint32_t h01=(u1&0xFFFF0000u)|(u0>>16), h23=(u3&0xFFFF0000u)|(u2>>16);
      uint32_t l0=f2u(k4.x-u2f(u0&0xFFFF0000u)), l1=f2u(k4.y-u2f(u1&0xFFFF0000u));
      uint32_t l2=f2u(k4.z-u2f(u2&0xFFFF0000u)), l3=f2u(k4.w-u2f(u3&0xFFFF0000u));
      uint32_t lo01=(l1&0xFFFF0000u)|(l0>>16), lo23=(l3&0xFFFF0000u)|(l2>>16);
      uint32_t off = ((uint32_t)(row*128 + c*2)) ^ ((uint32_t)((row&7)<<4));
      *(i32x2*)(khiB + off) = i32x2{(int)h01,(int)h23};
      *(i32x2*)(kloB + off) = i32x2{(int)lo01,(int)lo23};

      float4 v4 = *(const float4*)(Vp + (size_t)(kt0 + row) * 64 + c);
      uint32_t vp01, vp23;
      asm("v_cvt_pk_bf16_f32 %0, %1, %2" : "=v"(vp01) : "v"(v4.x), "v"(v4.y));
      asm("v_cvt_pk_bf16_f32 %0, %1, %2" : "=v"(vp23) : "v"(v4.z), "v"(v4.w));
      *(i32x2*)(vtsB + (uint32_t)(row*128 + c*2)) = i32x2{(int)vp01,(int)vp23};
    }
    __syncthreads();

    uint32_t mw;
    if constexpr (USE_WS) {
      mw = Mask[mrowbase + (uint32_t)((kt0 + h * 32) >> 5)];
    } else {
      uint32_t fb = (((uint32_t)b*4096u + qglob)*4096u) + (uint32_t)(kt0 + h*32);
      mw = 0u;
      for (uint32_t j = 0; j < 32u; ++j) mw |= (uint32_t)keep_partitionable(fb + j) << j;
    }

    // ---- QK^T: S^T = K * Q^T, 3-pass split bf16 ----
    f32x16 acc;
#pragma unroll
    for (int i = 0; i < 16; ++i) acc[i] = 0.f;
    bf16x8 kfrag[4];
    const uint32_t kswz = (uint32_t)((rowk&7)<<4);
#pragma unroll
    for (int kc = 0; kc < 4; ++kc) {
      uint32_t off = ((uint32_t)(rowk*128 + kc*32 + hi5*16)) ^ kswz;
      kfrag[kc] = *(const bf16x8*)(khiB + off);
    }
#pragma unroll
    for (int kc = 0; kc < 4; ++kc)
      acc = __builtin_amdgcn_mfma_f32_32x32x16_bf16(kfrag[kc], qhi[kc], acc, 0, 0, 0);
#pragma unroll
    for (int kc = 0; kc < 4; ++kc)
      acc = __builtin_amdgcn_mfma_f32_32x32x16_bf16(kfrag[kc], qlo[kc], acc, 0, 0, 0);
#pragma unroll
    for (int kc = 0; kc < 4; ++kc) {
      uint32_t off = ((uint32_t)(rowk*128 + kc*32 + hi5*16)) ^ kswz;
      kfrag[kc] = *(const bf16x8*)(kloB + off);
    }
#pragma unroll
    for (int kc = 0; kc < 4; ++kc)
      acc = __builtin_amdgcn_mfma_f32_32x32x16_bf16(kfrag[kc], qhi[kc], acc, 0, 0, 0);

    // ---- online softmax (lane-local: all 16 regs share q = l31) ----
    float z[16];
#pragma unroll
    for (int i = 0; i < 16; ++i) z[i] = acc[i] * inv_s;
    float tmax = z[0];
#pragma unroll
    for (int i = 1; i < 16; ++i) tmax = fmaxf(tmax, z[i]);
    tmax = fmaxf(tmax, __shfl_xor(tmax, 32));
    float mn = fmaxf(m, tmax);
    if (!__all(mn == m)) {
      float cr = __expf(m - mn);
      m = mn;
      lsum *= cr;
#pragma unroll
      for (int r = 0; r < 16; ++r) {
        int qr = (r & 3) + 8 * (r >> 2) + 4 * hi5;
        float cq = __shfl(cr, qr);
        o0[r] *= cq; o1[r] *= cq;
      }
    }
    float em[16];
#pragma unroll
    for (int r = 0; r < 16; ++r) {
      float e = __expf(z[r] - m);
      lsum += e;                                   // denominator: UNMASKED
      int bit = (r & 3) + 8 * (r >> 2) + 4 * hi5;  // kv-local index
      em[r] = ((mw >> bit) & 1u) ? e : 0.f;
    }

    // ---- P -> A-operand fragments (contiguous k = 8*hi5+j) via cvt_pk + shfl_xor(32) ----
    uint32_t cw[8];
#pragma unroll
    for (int i = 0; i < 8; ++i)
      asm("v_cvt_pk_bf16_f32 %0, %1, %2" : "=v"(cw[i]) : "v"(em[2*i]), "v"(em[2*i+1]));
    uint32_t sx[8];
#pragma unroll
    for (int i = 0; i < 8; ++i) sx[i] = (uint32_t)__shfl_xor((int)cw[i], 32);
    PU pf0, pf1;
    pf0.i = i32x4{ (int)(hi5 ? sx[2] : cw[0]),
                   (int)(hi5 ? sx[3] : cw[1]),
                   (int)(hi5 ? cw[2] : sx[0]),
                   (int)(hi5 ? cw[3] : sx[1]) };
    pf1.i = i32x4{ (int)(hi5 ? sx[6] : cw[4]),
                   (int)(hi5 ? sx[7] : cw[5]),
                   (int)(hi5 ? cw[6] : sx[4]),
                   (int)(hi5 ? cw[7] : sx[5]) };

    // ---- V B-fragments: scalar u16 gathers from row-major V tile ----
    PU vf00, vf01, vf10, vf11;
#pragma unroll
    for (int ks = 0; ks < 2; ++ks)
#pragma unroll
      for (int vb = 0; vb < 2; ++vb) {
        int wds[4];
#pragma unroll
        for (int jj = 0; jj < 4; ++jj) {
          int k0 = 32*h + 16*ks + 8*hi5 + 2*jj;
          uint32_t lo = *(const uint16_t*)(vtsB + k0*128     + (vb*32 + l31)*2);
          uint32_t hi = *(const uint16_t*)(vtsB + (k0+1)*128 + (vb*32 + l31)*2);
          wds[jj] = (int)(lo | (hi << 16));
        }
        PU tmp; tmp.i = i32x4{wds[0], wds[1], wds[2], wds[3]};
        if (ks == 0 && vb == 0) vf00 = tmp;
        else if (ks == 0 && vb == 1) vf01 = tmp;
        else if (ks == 1 && vb == 0) vf10 = tmp;
        else vf11 = tmp;
      }

    // ---- PV: O = P * V ----
    o0 = __builtin_amdgcn_mfma_f32_32x32x16_bf16(pf0.bv, vf00.bv, o0, 0, 0, 0);
    o0 = __builtin_amdgcn_mfma_f32_32x32x16_bf16(pf1.bv, vf10.bv, o0, 0, 0, 0);
    o1 = __builtin_amdgcn_mfma_f32_32x32x16_bf16(pf0.bv, vf01.bv, o1, 0, 0, 0);
    o1 = __builtin_amdgcn_mfma_f32_32x32x16_bf16(pf1.bv, vf11.bv, o1, 0, 0, 0);
    __syncthreads();
  }

  // ---- merge the 4 kv-quarters per q-group ----
  lsum += __shfl_xor(lsum, 32);
  if (h > 0) {
    if (lane < 32) { sm_ml[wq][h-1][0][l31] = m; sm_ml[wq][h-1][1][l31] = lsum; }
    float* dst = smf + (size_t)(wq * 3 + (h - 1)) * 2048;
#pragma unroll
    for (int r = 0; r < 16; ++r) {
      int qr = (r & 3) + 8 * (r >> 2) + 4 * hi5;
      dst[qr * 64 + l31]      = o0[r];
      dst[qr * 64 + 32 + l31] = o1[r];
    }
  }
  __syncthreads();
  if (h == 0) {
#pragma unroll
    for (int hp = 1; hp < 4; ++hp) {
      float mp = sm_ml[wq][hp-1][0][l31];
      float lp = sm_ml[wq][hp-1][1][l31];
      float mm = fmaxf(m, mp);
      float ca = __expf(m - mm);
      float cb = __expf(mp - mm);
      lsum = lsum * ca + lp * cb;
      m = mm;
      const float* srcp = smf + (size_t)(wq * 3 + (hp - 1)) * 2048;
#pragma unroll
      for (int r = 0; r < 16; ++r) {
        int qr = (r & 3) + 8 * (r >> 2) + 4 * hi5;
        float caq = __shfl(ca, qr);
        float cbq = __shfl(cb, qr);
        o0[r] = o0[r] * caq + srcp[qr * 64 + l31] * cbq;
        o1[r] = o1[r] * caq + srcp[qr * 64 + 32 + l31] * cbq;
      }
    }
    float rinv = 1.0f / (lsum * KEEP_P);
    float* op = Out + ((size_t)b * S_LEN + (size_t)(qt + wq * 32)) * 64;
#pragma unroll
    for (int r = 0; r < 16; ++r) {
      int qr = (r & 3) + 8 * (r >> 2) + 4 * hi5;
      float rq = __shfl(rinv, qr);
      op[(size_t)qr * 64 + l31]      = o0[r] * rq;
      op[(size_t)qr * 64 + 32 + l31] = o1[r] * rq;
    }
  }
}

extern "C" void kernel_launch(void* const* d_in, const int* in_sizes, int n_in,
                              void* d_out, int out_size, void* d_ws, size_t ws_size,
                              hipStream_t stream) {
  (void)in_sizes; (void)n_in; (void)out_size;
  const float* q = (const float*)d_in[0];
  const float* k = (const float*)d_in[1];
  const float* v = (const float*)d_in[2];
  const float* s = (const float*)d_in[3];
  float* out = (float*)d_out;

  const bool use_ws = ws_size >= (size_t)MASK_WORDS * sizeof(uint32_t);
  if (use_ws) {
    uint32_t* mask = (uint32_t*)d_ws;
    maskgen_kernel<<<MASK_WORDS / 256u, 256, 0, stream>>>(mask);  // 8192 blocks
    attn_mfma<true><<<dim3(256), dim3(512), 0, stream>>>(q, k, v, s, mask, out);
  } else {
    attn_mfma<false><<<dim3(256), dim3(512), 0, stream>>>(q, k, v, s, nullptr, out);
  }
}

// Round 9
// 201.823 us; speedup vs baseline: 1.0608x; 1.0608x over previous
//
#include <hip/hip_runtime.h>
#include <stdint.h>

#define S_LEN 4096
#define KEEP_P 0.991f

typedef __attribute__((ext_vector_type(8)))  short bf16x8;
typedef __attribute__((ext_vector_type(16))) float f32x16;
typedef __attribute__((ext_vector_type(4)))  int   i32x4;
typedef __attribute__((ext_vector_type(2)))  int   i32x2;

// keep  <=>  (o0^o1) < KEEP_TH  (integer form of u<0.991f; f32(0.991)=8313111*2^-23,
// u = m*2^-23 exactly (Sterbenz), so u<0.991 <=> m<8313111 <=> bits < 8313111<<9)
static constexpr uint32_t KEEP_TH = 4256312832u;        // 8313111 << 9

__device__ __forceinline__ uint32_t rotl32(uint32_t x, uint32_t r) {
#if __has_builtin(__builtin_amdgcn_alignbit)
  return __builtin_amdgcn_alignbit(x, x, 32u - r);      // v_alignbit_b32
#else
  return (x << r) | (x >> (32u - r));
#endif
}

// Exact JAX threefry2x32 for key = jax.random.key(1) -> (k0,k1)=(0,1)
// (C version: r6-proven codegen, ~90% issue efficiency when compiler-scheduled)
__device__ __forceinline__ void threefry(uint32_t x0, uint32_t x1,
                                         uint32_t& o0, uint32_t& o1) {
  const uint32_t k0 = 0u, k1 = 1u, k2 = 0x1BD11BDBu;
  uint32_t v0 = x0 + k0, v1 = x1 + k1;
#define TFR(r) { v0 += v1; v1 = rotl32(v1, (r)); v1 ^= v0; }
  TFR(13) TFR(15) TFR(26) TFR(6)
  v0 += k1; v1 += k2 + 1u;
  TFR(17) TFR(29) TFR(16) TFR(24)
  v0 += k2; v1 += k0 + 2u;
  TFR(13) TFR(15) TFR(26) TFR(6)
  v0 += k0; v1 += k1 + 3u;
  TFR(17) TFR(29) TFR(16) TFR(24)
  v0 += k1; v1 += k2 + 4u;
  TFR(13) TFR(15) TFR(26) TFR(6)
  v0 += k2; v1 += k0 + 5u;
#undef TFR
  o0 = v0; o1 = v1;
}

// jax_threefry_partitionable path: bits = o0^o1 of threefry(0, i)
__device__ __forceinline__ bool keep_partitionable(uint32_t i) {
  uint32_t o0, o1;
  threefry(0u, i, o0, o1);
  return (o0 ^ o1) < KEEP_TH;
}

__device__ __forceinline__ uint32_t f2u(float f){ union{float f;uint32_t u;}x; x.f=f; return x.u; }
__device__ __forceinline__ float u2f(uint32_t u){ union{uint32_t u;float f;}x; x.u=u; return x.f; }

__global__ __launch_bounds__(512, 2)
void attn_mfma(const float* __restrict__ Qg, const float* __restrict__ Kg,
               const float* __restrict__ Vg, const float* __restrict__ Sdiv,
               float* __restrict__ Out)
{
  __shared__ __align__(16) unsigned char smem[49152]; // khi 16K | klo 16K | v 16K
  __shared__ float sm_ml[2][3][2][32];
  char* khiB = (char*)smem;
  char* kloB = (char*)smem + 16384;
  char* vtsB = (char*)smem + 32768;
  float* smf = (float*)smem;   // epilogue scratch (reuse)

  const int t    = threadIdx.x;
  const int lane = t & 63;
  const int w    = t >> 6;     // wave 0..7
  const int wq   = w >> 2;     // q-group 0..1 (32 q each)
  const int h    = w & 3;      // kv quarter 0..3 (32 kv each)
  const int l31  = lane & 31;
  const int hi5  = lane >> 5;

  const int blk = blockIdx.x;
  const int xcd = blk & 7;
  const int b   = xcd >> 1;
  const int qblock = ((xcd & 1) << 5) | (blk >> 3);  // 0..63
  const int qt  = qblock * 64;

  const float inv_s = 1.0f / Sdiv[0];
  const float* Qp = Qg + (size_t)b * S_LEN * 64;
  const float* Kp = Kg + (size_t)b * S_LEN * 64;
  const float* Vp = Vg + (size_t)b * S_LEN * 64;

  // ---- stage Q (64 rows) hi/lo into khi/klo rows 0..63 (plain layout + XOR swizzle) ----
#pragma unroll
  for (int rr = 0; rr < 2; ++rr) {
    int row = rr * 32 + (t >> 4);
    int c   = (t & 15) * 4;
    float4 q4 = *(const float4*)(Qp + (size_t)(qt + row) * 64 + c);
    uint32_t u0=f2u(q4.x),u1=f2u(q4.y),u2=f2u(q4.z),u3=f2u(q4.w);
    uint32_t h01=(u1&0xFFFF0000u)|(u0>>16), h23=(u3&0xFFFF0000u)|(u2>>16);
    uint32_t l0=f2u(q4.x-u2f(u0&0xFFFF0000u)), l1=f2u(q4.y-u2f(u1&0xFFFF0000u));
    uint32_t l2=f2u(q4.z-u2f(u2&0xFFFF0000u)), l3=f2u(q4.w-u2f(u3&0xFFFF0000u));
    uint32_t lo01=(l1&0xFFFF0000u)|(l0>>16), lo23=(l3&0xFFFF0000u)|(l2>>16);
    uint32_t off = ((uint32_t)(row*128 + c*2)) ^ ((uint32_t)((row&7)<<4));
    *(i32x2*)(khiB + off) = i32x2{(int)h01,(int)h23};
    *(i32x2*)(kloB + off) = i32x2{(int)lo01,(int)lo23};
  }
  __syncthreads();
  bf16x8 qhi[4], qlo[4];
  {
    int qrow = wq * 32 + l31;
#pragma unroll
    for (int kc = 0; kc < 4; ++kc) {
      uint32_t off = ((uint32_t)(qrow*128 + kc*32 + hi5*16)) ^ ((uint32_t)((qrow&7)<<4));
      qhi[kc] = *(const bf16x8*)(khiB + off);
      qlo[kc] = *(const bf16x8*)(kloB + off);
    }
  }
  __syncthreads();

  f32x16 o0, o1;
#pragma unroll
  for (int i = 0; i < 16; ++i) { o0[i] = 0.f; o1[i] = 0.f; }
  float m = -INFINITY, lsum = 0.f;

  const int rowk = h * 32 + l31;
  const uint32_t qglob = (uint32_t)(qt + wq * 32 + l31);
  // flat-index base for this lane's mask bits: row qglob, col block (h*32 + 4*hi5)
  const uint32_t fbrow = (((uint32_t)b * 4096u + qglob) * 4096u)
                       + (uint32_t)(h * 32) + 4u * (uint32_t)hi5;

  union PU { i32x4 i; bf16x8 bv; };

  for (int kt0 = 0; kt0 < S_LEN; kt0 += 128) {
    // ---- stage K (hi/lo, plain+swizzle) and V (plain row-major bf16 [128][64]) ----
#pragma unroll
    for (int rr = 0; rr < 4; ++rr) {
      int row = rr * 32 + (t >> 4);
      int c   = (t & 15) * 4;
      float4 k4 = *(const float4*)(Kp + (size_t)(kt0 + row) * 64 + c);
      uint32_t u0=f2u(k4.x),u1=f2u(k4.y),u2=f2u(k4.z),u3=f2u(k4.w);
      uint32_t h01=(u1&0xFFFF0000u)|(u0>>16), h23=(u3&0xFFFF0000u)|(u2>>16);
      uint32_t l0=f2u(k4.x-u2f(u0&0xFFFF0000u)), l1=f2u(k4.y-u2f(u1&0xFFFF0000u));
      uint32_t l2=f2u(k4.z-u2f(u2&0xFFFF0000u)), l3=f2u(k4.w-u2f(u3&0xFFFF0000u));
      uint32_t lo01=(l1&0xFFFF0000u)|(l0>>16), lo23=(l3&0xFFFF0000u)|(l2>>16);
      uint32_t off = ((uint32_t)(row*128 + c*2)) ^ ((uint32_t)((row&7)<<4));
      *(i32x2*)(khiB + off) = i32x2{(int)h01,(int)h23};
      *(i32x2*)(kloB + off) = i32x2{(int)lo01,(int)lo23};

      float4 v4 = *(const float4*)(Vp + (size_t)(kt0 + row) * 64 + c);
      uint32_t vp01, vp23;
      asm("v_cvt_pk_bf16_f32 %0, %1, %2" : "=v"(vp01) : "v"(v4.x), "v"(v4.y));
      asm("v_cvt_pk_bf16_f32 %0, %1, %2" : "=v"(vp23) : "v"(v4.z), "v"(v4.w));
      *(i32x2*)(vtsB + (uint32_t)(row*128 + c*2)) = i32x2{(int)vp01,(int)vp23};
    }
    __syncthreads();

    // ---- fused dropout mask: this lane needs only bits (8p + 4*hi5 + q) ----
    // (fbrow already includes the +4*hi5 column offset)
    uint32_t mw = 0u;
    {
      const uint32_t fb = fbrow + (uint32_t)kt0;
#pragma unroll
      for (int p = 0; p < 4; ++p)
#pragma unroll
        for (int q = 0; q < 4; ++q) {
          uint32_t bitpos = (uint32_t)(8 * p + 4 * hi5 + q);
          mw |= (uint32_t)keep_partitionable(fb + (uint32_t)(8 * p + q)) << bitpos;
        }
    }

    // ---- QK^T: S^T = K * Q^T, 3-pass split bf16 ----
    f32x16 acc;
#pragma unroll
    for (int i = 0; i < 16; ++i) acc[i] = 0.f;
    bf16x8 kfrag[4];
    const uint32_t kswz = (uint32_t)((rowk&7)<<4);
#pragma unroll
    for (int kc = 0; kc < 4; ++kc) {
      uint32_t off = ((uint32_t)(rowk*128 + kc*32 + hi5*16)) ^ kswz;
      kfrag[kc] = *(const bf16x8*)(khiB + off);
    }
#pragma unroll
    for (int kc = 0; kc < 4; ++kc)
      acc = __builtin_amdgcn_mfma_f32_32x32x16_bf16(kfrag[kc], qhi[kc], acc, 0, 0, 0);
#pragma unroll
    for (int kc = 0; kc < 4; ++kc)
      acc = __builtin_amdgcn_mfma_f32_32x32x16_bf16(kfrag[kc], qlo[kc], acc, 0, 0, 0);
#pragma unroll
    for (int kc = 0; kc < 4; ++kc) {
      uint32_t off = ((uint32_t)(rowk*128 + kc*32 + hi5*16)) ^ kswz;
      kfrag[kc] = *(const bf16x8*)(kloB + off);
    }
#pragma unroll
    for (int kc = 0; kc < 4; ++kc)
      acc = __builtin_amdgcn_mfma_f32_32x32x16_bf16(kfrag[kc], qhi[kc], acc, 0, 0, 0);

    // ---- online softmax (lane-local: all 16 regs share q = l31) ----
    float z[16];
#pragma unroll
    for (int i = 0; i < 16; ++i) z[i] = acc[i] * inv_s;
    float tmax = z[0];
#pragma unroll
    for (int i = 1; i < 16; ++i) tmax = fmaxf(tmax, z[i]);
    tmax = fmaxf(tmax, __shfl_xor(tmax, 32));
    float mn = fmaxf(m, tmax);
    if (!__all(mn == m)) {
      float cr = __expf(m - mn);
      m = mn;
      lsum *= cr;
#pragma unroll
      for (int r = 0; r < 16; ++r) {
        int qr = (r & 3) + 8 * (r >> 2) + 4 * hi5;
        float cq = __shfl(cr, qr);
        o0[r] *= cq; o1[r] *= cq;
      }
    }
    float em[16];
#pragma unroll
    for (int r = 0; r < 16; ++r) {
      float e = __expf(z[r] - m);
      lsum += e;                                   // denominator: UNMASKED
      int bit = (r & 3) + 8 * (r >> 2) + 4 * hi5;  // kv-local index
      em[r] = ((mw >> bit) & 1u) ? e : 0.f;
    }

    // ---- P -> A-operand fragments (contiguous k = 8*hi5+j) via cvt_pk + shfl_xor(32) ----
    uint32_t cw[8];
#pragma unroll
    for (int i = 0; i < 8; ++i)
      asm("v_cvt_pk_bf16_f32 %0, %1, %2" : "=v"(cw[i]) : "v"(em[2*i]), "v"(em[2*i+1]));
    uint32_t sx[8];
#pragma unroll
    for (int i = 0; i < 8; ++i) sx[i] = (uint32_t)__shfl_xor((int)cw[i], 32);
    PU pf0, pf1;
    pf0.i = i32x4{ (int)(hi5 ? sx[2] : cw[0]),
                   (int)(hi5 ? sx[3] : cw[1]),
                   (int)(hi5 ? cw[2] : sx[0]),
                   (int)(hi5 ? cw[3] : sx[1]) };
    pf1.i = i32x4{ (int)(hi5 ? sx[6] : cw[4]),
                   (int)(hi5 ? sx[7] : cw[5]),
                   (int)(hi5 ? cw[6] : sx[4]),
                   (int)(hi5 ? cw[7] : sx[5]) };

    // ---- V B-fragments: scalar u16 gathers from row-major V tile ----
    PU vf00, vf01, vf10, vf11;
#pragma unroll
    for (int ks = 0; ks < 2; ++ks)
#pragma unroll
      for (int vb = 0; vb < 2; ++vb) {
        int wds[4];
#pragma unroll
        for (int jj = 0; jj < 4; ++jj) {
          int k0 = 32*h + 16*ks + 8*hi5 + 2*jj;
          uint32_t lo = *(const uint16_t*)(vtsB + k0*128     + (vb*32 + l31)*2);
          uint32_t hi = *(const uint16_t*)(vtsB + (k0+1)*128 + (vb*32 + l31)*2);
          wds[jj] = (int)(lo | (hi << 16));
        }
        PU tmp; tmp.i = i32x4{wds[0], wds[1], wds[2], wds[3]};
        if (ks == 0 && vb == 0) vf00 = tmp;
        else if (ks == 0 && vb == 1) vf01 = tmp;
        else if (ks == 1 && vb == 0) vf10 = tmp;
        else vf11 = tmp;
      }

    // ---- PV: O = P * V ----
    o0 = __builtin_amdgcn_mfma_f32_32x32x16_bf16(pf0.bv, vf00.bv, o0, 0, 0, 0);
    o0 = __builtin_amdgcn_mfma_f32_32x32x16_bf16(pf1.bv, vf10.bv, o0, 0, 0, 0);
    o1 = __builtin_amdgcn_mfma_f32_32x32x16_bf16(pf0.bv, vf01.bv, o1, 0, 0, 0);
    o1 = __builtin_amdgcn_mfma_f32_32x32x16_bf16(pf1.bv, vf11.bv, o1, 0, 0, 0);
    __syncthreads();
  }

  // ---- merge the 4 kv-quarters per q-group ----
  lsum += __shfl_xor(lsum, 32);
  if (h > 0) {
    if (lane < 32) { sm_ml[wq][h-1][0][l31] = m; sm_ml[wq][h-1][1][l31] = lsum; }
    float* dst = smf + (size_t)(wq * 3 + (h - 1)) * 2048;
#pragma unroll
    for (int r = 0; r < 16; ++r) {
      int qr = (r & 3) + 8 * (r >> 2) + 4 * hi5;
      dst[qr * 64 + l31]      = o0[r];
      dst[qr * 64 + 32 + l31] = o1[r];
    }
  }
  __syncthreads();
  if (h == 0) {
#pragma unroll
    for (int hp = 1; hp < 4; ++hp) {
      float mp = sm_ml[wq][hp-1][0][l31];
      float lp = sm_ml[wq][hp-1][1][l31];
      float mm = fmaxf(m, mp);
      float ca = __expf(m - mm);
      float cb = __expf(mp - mm);
      lsum = lsum * ca + lp * cb;
      m = mm;
      const float* srcp = smf + (size_t)(wq * 3 + (hp - 1)) * 2048;
#pragma unroll
      for (int r = 0; r < 16; ++r) {
        int qr = (r & 3) + 8 * (r >> 2) + 4 * hi5;
        float caq = __shfl(ca, qr);
        float cbq = __shfl(cb, qr);
        o0[r] = o0[r] * caq + srcp[qr * 64 + l31] * cbq;
        o1[r] = o1[r] * caq + srcp[qr * 64 + 32 + l31] * cbq;
      }
    }
    float rinv = 1.0f / (lsum * KEEP_P);
    float* op = Out + ((size_t)b * S_LEN + (size_t)(qt + wq * 32)) * 64;
#pragma unroll
    for (int r = 0; r < 16; ++r) {
      int qr = (r & 3) + 8 * (r >> 2) + 4 * hi5;
      float rq = __shfl(rinv, qr);
      op[(size_t)qr * 64 + l31]      = o0[r] * rq;
      op[(size_t)qr * 64 + 32 + l31] = o1[r] * rq;
    }
  }
}

extern "C" void kernel_launch(void* const* d_in, const int* in_sizes, int n_in,
                              void* d_out, int out_size, void* d_ws, size_t ws_size,
                              hipStream_t stream) {
  (void)in_sizes; (void)n_in; (void)out_size; (void)d_ws; (void)ws_size;
  const float* q = (const float*)d_in[0];
  const float* k = (const float*)d_in[1];
  const float* v = (const float*)d_in[2];
  const float* s = (const float*)d_in[3];
  float* out = (float*)d_out;

  attn_mfma<<<dim3(256), dim3(512), 0, stream>>>(q, k, v, s, out);
}